// Round 8
// baseline (5665.017 us; speedup 1.0000x reference)
//
#include <hip/hip_runtime.h>
#include <hip/hip_cooperative_groups.h>
#include <hip/hip_bf16.h>
#include <math.h>

namespace cg = cooperative_groups;

// Problem constants
#define NB       128
#define P_HW     196
#define ENC_C    2048
#define V_SZ     10000
#define E_SZ     512
#define D_SZ     512
#define MAXLEN   32
#define T_STEPS  31

// d_out layout (floats), in reference return order
#define SZ_PRED    (128ULL * 31ULL * 10000ULL)
#define OFF_PRED   0ULL
#define OFF_CAPT   (SZ_PRED)
#define OFF_DECLEN (OFF_CAPT + 128ULL * 32ULL)
#define OFF_ALPHA  (OFF_DECLEN + 128ULL)
#define OFF_SORT   (OFF_ALPHA + 128ULL * 31ULL * 196ULL)

typedef __bf16 bf16x8 __attribute__((ext_vector_type(8)));
typedef float f32x4 __attribute__((ext_vector_type(4)));

__device__ __forceinline__ float sigf(float x) { return 1.0f / (1.0f + __expf(-x)); }

__device__ __forceinline__ unsigned short f2bf(float f) {
    unsigned int u = __float_as_uint(f);
    unsigned int r = (u + 0x7fffu + ((u >> 16) & 1u)) >> 16;  // RNE
    return (unsigned short)r;
}

// ---------------------------------------------------------------------------
// Stable descending sort by caption length (rank via O(N^2) count)
// ---------------------------------------------------------------------------
__global__ void sort_kernel(const int* __restrict__ capt_lengths,
                            const int* __restrict__ enc_capt,
                            int* __restrict__ sort_ind_ws,
                            int* __restrict__ dec_len_ws,
                            int* __restrict__ capt_sorted_ws,
                            float* __restrict__ dout) {
    __shared__ int cl[NB];
    int i = threadIdx.x;
    cl[i] = capt_lengths[i];
    __syncthreads();
    int my = cl[i];
    int rank = 0;
    #pragma unroll 4
    for (int j = 0; j < NB; ++j) {
        int cj = cl[j];
        rank += (cj > my) || (cj == my && j < i);
    }
    sort_ind_ws[rank] = i;
    dec_len_ws[rank]  = my - 1;
    dout[OFF_SORT + rank]   = (float)i;
    dout[OFF_DECLEN + rank] = (float)(my - 1);
    for (int t = 0; t < MAXLEN; ++t) {
        int tok = enc_capt[i * MAXLEN + t];
        capt_sorted_ws[rank * MAXLEN + t] = tok;
        dout[OFF_CAPT + rank * MAXLEN + t] = (float)tok;
    }
}

// ---------------------------------------------------------------------------
// mean_feat[b, e] = mean over 196 positions; writes fp32 + bf16 copies
// ---------------------------------------------------------------------------
__global__ void mean_kernel(const float* __restrict__ enc_feature,
                            const int* __restrict__ sort_ind,
                            float* __restrict__ mean_feat,
                            unsigned short* __restrict__ mean16) {
    int b = blockIdx.y;
    int e = blockIdx.x * 256 + threadIdx.x;
    int src = sort_ind[b];
    const float* base = enc_feature + (size_t)src * P_HW * ENC_C + e;
    float s = 0.0f;
    #pragma unroll 4
    for (int p = 0; p < P_HW; ++p) s += base[(size_t)p * ENC_C];
    float m = s * (1.0f / (float)P_HW);
    mean_feat[(size_t)b * ENC_C + e] = m;
    mean16[(size_t)b * ENC_C + e] = f2bf(m);
}

// ---------------------------------------------------------------------------
__global__ void f32_to_bf16(const float* __restrict__ src,
                            unsigned short* __restrict__ dst, int n) {
    int i = (blockIdx.x * 256 + threadIdx.x) * 4;
    if (i < n) {
        float4 v = *reinterpret_cast<const float4*>(src + i);
        dst[i + 0] = f2bf(v.x);
        dst[i + 1] = f2bf(v.y);
        dst[i + 2] = f2bf(v.z);
        dst[i + 3] = f2bf(v.w);
    }
}

// Gate-interleaved packed Wg: packed row p = d*4 + gate  (d = n&511, g = n>>9)
// WgP[p][0:2560] = W_ih[n], WgP[p][2560:3072] = W_hh[n]
__global__ void concat_wg(const float* __restrict__ W_ih,
                          const float* __restrict__ W_hh,
                          unsigned short* __restrict__ WgP) {
    int n = blockIdx.y;
    int col = blockIdx.x * 256 + threadIdx.x;  // < 3072
    float v = (col < 2560) ? W_ih[(size_t)n * 2560 + col]
                           : W_hh[(size_t)n * 512 + (col - 2560)];
    int p = ((n & 511) << 2) | (n >> 9);
    WgP[(size_t)p * 3072 + col] = f2bf(v);
}

__global__ void bsum_kernel(const float* __restrict__ b_ih,
                            const float* __restrict__ b_hh,
                            float* __restrict__ bsumP) {
    int i = blockIdx.x * 256 + threadIdx.x;  // 2048
    bsumP[((i & 511) << 2) | (i >> 9)] = b_ih[i] + b_hh[i];
}

// embs16[t][b][e] = bf16(emb[capt_sorted[b][t]][e])
__global__ void embs_gather(const float* __restrict__ emb,
                            const int* __restrict__ capt_sorted,
                            unsigned short* __restrict__ embs16) {
    int idx = blockIdx.x * 256 + threadIdx.x;  // 31*128*512
    if (idx >= 31 * 128 * 512) return;
    int t = idx >> 16;
    int r = idx & 65535;
    int b = r >> 9;
    int tok = capt_sorted[b * MAXLEN + t];
    embs16[idx] = f2bf(emb[(size_t)tok * E_SZ + (r & 511)]);
}

// ---------------------------------------------------------------------------
// Persistent cooperative kernel: init GEMMs + 31 LSTM steps.
// 256 blocks x 512 threads (8 waves). Per phase each block owns a 32x32 tile,
// 8-wave K-split with LDS reduce. XCD-partitioned N so weight slabs stay in
// the owning XCD's L2 across steps. h ping-pong; fence+grid.sync between
// phases for cross-XCD visibility.
// ---------------------------------------------------------------------------
struct PP {
    const unsigned short* mean16;
    const float* mean_feat;
    const unsigned short* Wfb;     // 2048 x 512
    const float* b_fbeta;
    const unsigned short* WgP;     // packed 2048 x 3072
    const float* bsumP;            // packed 2048
    const unsigned short* Winith;  // 512 x 2048
    const float* b_inith;
    const unsigned short* Winitc;  // 512 x 2048
    const float* b_initc;
    const unsigned short* embs;    // [31][128][512]
    float* c;                      // 128 x 512 fp32
    unsigned short* h0;            // ping
    unsigned short* h1;            // pong
    unsigned short* awe;           // 128 x 2048 bf16
    unsigned short* hnew_all;      // [31][128][512] bf16
    const int* dec_len;
};

__global__ __launch_bounds__(512, 2) void persistent_kernel(PP p) {
    cg::grid_group grid = cg::this_grid();
    __shared__ float red[8][1024];
    int blk = blockIdx.x, tid = threadIdx.x;
    int w = tid >> 6, l = tid & 63;
    int lm = l & 15, lk = (l >> 4) << 3;
    int orow = (l >> 4) << 2;
    // tile mapping for phases A/B: XCD owns a contiguous N-slice
    int xcd = blk & 7, jj = blk >> 3;
    int bm = jj & 3, bn = (xcd << 3) + (jj >> 2);  // bm in [0,4), bn in [0,64)

    // ---------------- phase 0: h0 = mean@Winith^T + b ; c0 = mean@Winitc^T + b
    if (blk < 128) {
        int sel = blk >> 6;           // 0: h0, 1: c0
        int j = blk & 63;
        int row0 = (j >> 4) << 5, col0 = (j & 15) << 5;
        const unsigned short* W = sel ? p.Winitc : p.Winith;
        const unsigned short* pa0 = p.mean16 + (size_t)(row0 + lm) * 2048 + lk;
        const unsigned short* pa1 = pa0 + 16 * 2048;
        const unsigned short* pb0 = W + (size_t)(col0 + lm) * 2048 + lk;
        const unsigned short* pb1 = pb0 + 16 * 2048;
        f32x4 a00 = {0.f,0.f,0.f,0.f}, a01 = a00, a10 = a00, a11 = a00;
        int k0 = w << 8;
        #pragma unroll 4
        for (int kk = 0; kk < 256; kk += 32) {
            int k = k0 + kk;
            bf16x8 av0 = *(const bf16x8*)(pa0 + k);
            bf16x8 av1 = *(const bf16x8*)(pa1 + k);
            bf16x8 bv0 = *(const bf16x8*)(pb0 + k);
            bf16x8 bv1 = *(const bf16x8*)(pb1 + k);
            a00 = __builtin_amdgcn_mfma_f32_16x16x32_bf16(av0, bv0, a00, 0, 0, 0);
            a01 = __builtin_amdgcn_mfma_f32_16x16x32_bf16(av0, bv1, a01, 0, 0, 0);
            a10 = __builtin_amdgcn_mfma_f32_16x16x32_bf16(av1, bv0, a10, 0, 0, 0);
            a11 = __builtin_amdgcn_mfma_f32_16x16x32_bf16(av1, bv1, a11, 0, 0, 0);
        }
        #pragma unroll
        for (int mi = 0; mi < 2; ++mi)
            #pragma unroll
            for (int ni = 0; ni < 2; ++ni) {
                f32x4 v = (mi == 0) ? (ni == 0 ? a00 : a01) : (ni == 0 ? a10 : a11);
                #pragma unroll
                for (int r = 0; r < 4; ++r)
                    red[w][(mi * 16 + orow + r) * 32 + ni * 16 + lm] = v[r];
            }
        __syncthreads();
        if (tid < 256) {
            float4 s = {0.f, 0.f, 0.f, 0.f};
            #pragma unroll
            for (int ww = 0; ww < 8; ++ww) {
                float4 v = *(const float4*)&red[ww][tid * 4];
                s.x += v.x; s.y += v.y; s.z += v.z; s.w += v.w;
            }
            int row = row0 + (tid >> 3), c4 = col0 + ((tid & 7) << 2);
            if (sel == 0) {
                float4 b = *(const float4*)&p.b_inith[c4];
                ushort4 o;
                o.x = f2bf(s.x + b.x); o.y = f2bf(s.y + b.y);
                o.z = f2bf(s.z + b.z); o.w = f2bf(s.w + b.w);
                *(ushort4*)&p.h0[(size_t)row * 512 + c4] = o;
            } else {
                float4 b = *(const float4*)&p.b_initc[c4];
                float4 o = {s.x + b.x, s.y + b.y, s.z + b.z, s.w + b.w};
                *(float4*)&p.c[(size_t)row * 512 + c4] = o;
            }
        }
    }
    __threadfence();
    grid.sync();

    for (int t = 0; t < T_STEPS; ++t) {
        const unsigned short* hin = (t & 1) ? p.h1 : p.h0;
        unsigned short* hout      = (t & 1) ? p.h0 : p.h1;
        // ------------- phase A: awe = bf16(mean * sigmoid(h @ Wfb^T + b))
        {
            int row0 = bm << 5, col0 = bn << 5;
            const unsigned short* pa0 = hin + (size_t)(row0 + lm) * 512 + lk;
            const unsigned short* pa1 = pa0 + 16 * 512;
            const unsigned short* pb0 = p.Wfb + (size_t)(col0 + lm) * 512 + lk;
            const unsigned short* pb1 = pb0 + 16 * 512;
            f32x4 a00 = {0.f,0.f,0.f,0.f}, a01 = a00, a10 = a00, a11 = a00;
            int k0 = w << 6;  // 8 waves x 64
            #pragma unroll
            for (int kk = 0; kk < 64; kk += 32) {
                int k = k0 + kk;
                bf16x8 av0 = *(const bf16x8*)(pa0 + k);
                bf16x8 av1 = *(const bf16x8*)(pa1 + k);
                bf16x8 bv0 = *(const bf16x8*)(pb0 + k);
                bf16x8 bv1 = *(const bf16x8*)(pb1 + k);
                a00 = __builtin_amdgcn_mfma_f32_16x16x32_bf16(av0, bv0, a00, 0, 0, 0);
                a01 = __builtin_amdgcn_mfma_f32_16x16x32_bf16(av0, bv1, a01, 0, 0, 0);
                a10 = __builtin_amdgcn_mfma_f32_16x16x32_bf16(av1, bv0, a10, 0, 0, 0);
                a11 = __builtin_amdgcn_mfma_f32_16x16x32_bf16(av1, bv1, a11, 0, 0, 0);
            }
            #pragma unroll
            for (int mi = 0; mi < 2; ++mi)
                #pragma unroll
                for (int ni = 0; ni < 2; ++ni) {
                    f32x4 v = (mi == 0) ? (ni == 0 ? a00 : a01) : (ni == 0 ? a10 : a11);
                    #pragma unroll
                    for (int r = 0; r < 4; ++r)
                        red[w][(mi * 16 + orow + r) * 32 + ni * 16 + lm] = v[r];
                }
            __syncthreads();
            if (tid < 256) {
                float4 s = {0.f, 0.f, 0.f, 0.f};
                #pragma unroll
                for (int ww = 0; ww < 8; ++ww) {
                    float4 v = *(const float4*)&red[ww][tid * 4];
                    s.x += v.x; s.y += v.y; s.z += v.z; s.w += v.w;
                }
                int row = row0 + (tid >> 3), c4 = col0 + ((tid & 7) << 2);
                float4 b = *(const float4*)&p.b_fbeta[c4];
                const float* mf = p.mean_feat + (size_t)row * 2048 + c4;
                ushort4 o;
                o.x = f2bf(mf[0] * sigf(s.x + b.x));
                o.y = f2bf(mf[1] * sigf(s.y + b.y));
                o.z = f2bf(mf[2] * sigf(s.z + b.z));
                o.w = f2bf(mf[3] * sigf(s.w + b.w));
                *(ushort4*)&p.awe[(size_t)row * 2048 + c4] = o;
            }
        }
        __threadfence();
        grid.sync();
        // ------------- phase B: gates GEMM (packed) + LSTM pointwise
        {
            int row0 = bm << 5;
            int p0 = bn << 5;      // packed col tile
            int d0 = bn << 3;      // 8 d-values
            int ra = row0 + lm;
            const unsigned short* embt = p.embs + (size_t)t * 65536;
            const unsigned short* pe0 = embt + (size_t)ra * 512 + lk;
            const unsigned short* pe1 = pe0 + 16 * 512;
            const unsigned short* pw0 = p.awe + (size_t)ra * 2048 + lk;
            const unsigned short* pw1 = pw0 + 16 * 2048;
            const unsigned short* ph0 = hin + (size_t)ra * 512 + lk;
            const unsigned short* ph1 = ph0 + 16 * 512;
            const unsigned short* pb0 = p.WgP + (size_t)(p0 + lm) * 3072 + lk;
            const unsigned short* pb1 = pb0 + (size_t)16 * 3072;
            f32x4 a00 = {0.f,0.f,0.f,0.f}, a01 = a00, a10 = a00, a11 = a00;
            int k0 = w * 384;
            #pragma unroll 4
            for (int kk = 0; kk < 384; kk += 32) {
                int k = k0 + kk;
                bf16x8 av0, av1;
                if (k < 512)       { av0 = *(const bf16x8*)(pe0 + k);
                                     av1 = *(const bf16x8*)(pe1 + k); }
                else if (k < 2560) { av0 = *(const bf16x8*)(pw0 + (k - 512));
                                     av1 = *(const bf16x8*)(pw1 + (k - 512)); }
                else               { av0 = *(const bf16x8*)(ph0 + (k - 2560));
                                     av1 = *(const bf16x8*)(ph1 + (k - 2560)); }
                bf16x8 bv0 = *(const bf16x8*)(pb0 + k);
                bf16x8 bv1 = *(const bf16x8*)(pb1 + k);
                a00 = __builtin_amdgcn_mfma_f32_16x16x32_bf16(av0, bv0, a00, 0, 0, 0);
                a01 = __builtin_amdgcn_mfma_f32_16x16x32_bf16(av0, bv1, a01, 0, 0, 0);
                a10 = __builtin_amdgcn_mfma_f32_16x16x32_bf16(av1, bv0, a10, 0, 0, 0);
                a11 = __builtin_amdgcn_mfma_f32_16x16x32_bf16(av1, bv1, a11, 0, 0, 0);
            }
            #pragma unroll
            for (int mi = 0; mi < 2; ++mi)
                #pragma unroll
                for (int ni = 0; ni < 2; ++ni) {
                    f32x4 v = (mi == 0) ? (ni == 0 ? a00 : a01) : (ni == 0 ? a10 : a11);
                    #pragma unroll
                    for (int r = 0; r < 4; ++r)
                        red[w][(mi * 16 + orow + r) * 32 + ni * 16 + lm] = v[r];
                }
            __syncthreads();
            if (tid < 256) {
                float4 s = {0.f, 0.f, 0.f, 0.f};
                #pragma unroll
                for (int ww = 0; ww < 8; ++ww) {
                    float4 v = *(const float4*)&red[ww][tid * 4];
                    s.x += v.x; s.y += v.y; s.z += v.z; s.w += v.w;
                }
                int row = tid >> 3, dloc = tid & 7;
                float4 bs = *(const float4*)&p.bsumP[p0 + dloc * 4];
                float gi = s.x + bs.x, gf = s.y + bs.y;
                float gg = s.z + bs.z, go = s.w + bs.w;
                int R = row0 + row, D = d0 + dloc;
                size_t idx = (size_t)R * 512 + D;
                float cn = sigf(gf) * p.c[idx] + sigf(gi) * tanhf(gg);
                float hn = sigf(go) * tanhf(cn);
                unsigned short hb = f2bf(hn);
                p.hnew_all[(size_t)t * 65536 + idx] = hb;
                if (t < p.dec_len[R]) {
                    p.c[idx] = cn;
                    hout[idx] = hb;
                } else {
                    hout[idx] = hin[idx];
                }
            }
        }
        __threadfence();
        grid.sync();
    }
}

// ---------------------------------------------------------------------------
// Batched fc with XCD-bijective tiling: each XCD owns ~10 N-panels and sweeps
// M fast within a panel -> Wfc panel fetched by one XCD, hnew L2-local.
// 128x128 tiles, 4 waves. grid 2480 blocks x 256 threads.
// ---------------------------------------------------------------------------
__global__ __launch_bounds__(256) void fc128x(
    const unsigned short* __restrict__ hnew_all,  // [3968][512]
    const unsigned short* __restrict__ Wfc,
    const float* __restrict__ b_fc,
    const int* __restrict__ dec_len,
    float* __restrict__ out) {
    int bidx = blockIdx.x;
    int xcd = bidx & 7;
    int j = bidx >> 3;          // [0,310)
    int m = j % 31;             // M fast within XCD
    int n = xcd * 10 + j / 31;  // [0,80)
    if (n >= 79) return;
    int tid = threadIdx.x;
    int w = tid >> 6, l = tid & 63;
    int wm = w >> 1, wn = w & 1;
    int lm = l & 15, lk = ((l >> 4) << 3);
    int row0 = m * 128 + wm * 64;
    int col0 = n * 128 + wn * 64;
    const unsigned short* pa[4];
    const unsigned short* pb[4];
    #pragma unroll
    for (int i = 0; i < 4; ++i) {
        pa[i] = hnew_all + (size_t)(row0 + i * 16 + lm) * 512 + lk;
        int bn = col0 + i * 16 + lm; if (bn > 9999) bn = 9999;
        pb[i] = Wfc + (size_t)bn * 512 + lk;
    }
    f32x4 acc[4][4];
    #pragma unroll
    for (int i = 0; i < 4; ++i)
        #pragma unroll
        for (int jq = 0; jq < 4; ++jq) acc[i][jq] = (f32x4){0.f, 0.f, 0.f, 0.f};
    for (int k = 0; k < 512; k += 32) {
        bf16x8 a[4], b[4];
        #pragma unroll
        for (int i = 0; i < 4; ++i) a[i] = *(const bf16x8*)(pa[i] + k);
        #pragma unroll
        for (int jq = 0; jq < 4; ++jq) b[jq] = *(const bf16x8*)(pb[jq] + k);
        #pragma unroll
        for (int i = 0; i < 4; ++i)
            #pragma unroll
            for (int jq = 0; jq < 4; ++jq)
                acc[i][jq] = __builtin_amdgcn_mfma_f32_16x16x32_bf16(a[i], b[jq], acc[i][jq], 0, 0, 0);
    }
    int orow = (l >> 4) << 2;
    #pragma unroll
    for (int i = 0; i < 4; ++i) {
        #pragma unroll
        for (int jq = 0; jq < 4; ++jq) {
            int col = col0 + jq * 16 + lm;
            if (col >= 10000) continue;
            float bias = b_fc[col];
            #pragma unroll
            for (int r = 0; r < 4; ++r) {
                int row = row0 + i * 16 + orow + r;
                int t = row >> 7, b = row & 127;
                bool msk = t < dec_len[b];
                out[OFF_PRED + ((size_t)b * 31 + t) * 10000 + col] =
                    msk ? (acc[i][jq][r] + bias) : 0.0f;
            }
        }
    }
}

// ---------------------------------------------------------------------------
__global__ void alphas_kernel(const int* __restrict__ dec_len,
                              float* __restrict__ dout) {
    int idx = blockIdx.x * 256 + threadIdx.x;  // 777728
    int b = idx / (31 * 196);
    int r = idx % (31 * 196);
    int t = r / 196;
    dout[OFF_ALPHA + idx] = (t < dec_len[b]) ? (1.0f / 196.0f) : 0.0f;
}

// ---------------------------------------------------------------------------
static inline char* align256(char* p) {
    return (char*)(((uintptr_t)p + 255) & ~(uintptr_t)255);
}

extern "C" void kernel_launch(void* const* d_in, const int* in_sizes, int n_in,
                              void* d_out, int out_size, void* d_ws, size_t ws_size,
                              hipStream_t stream) {
    const float* enc_feature  = (const float*)d_in[0];
    const int*   enc_capt     = (const int*)d_in[1];
    const int*   capt_lengths = (const int*)d_in[2];
    const float* emb     = (const float*)d_in[3];
    const float* W_ih    = (const float*)d_in[4];
    const float* b_ih    = (const float*)d_in[5];
    const float* W_hh    = (const float*)d_in[6];
    const float* b_hh    = (const float*)d_in[7];
    const float* W_inith = (const float*)d_in[8];
    const float* b_inith = (const float*)d_in[9];
    const float* W_initc = (const float*)d_in[10];
    const float* b_initc = (const float*)d_in[11];
    const float* W_fbeta = (const float*)d_in[12];
    const float* b_fbeta = (const float*)d_in[13];
    const float* W_fc    = (const float*)d_in[14];
    const float* b_fc    = (const float*)d_in[15];
    float* out = (float*)d_out;

    char* ws = (char*)d_ws;
    int* sort_ind    = (int*)ws;  ws += 512;
    int* dec_len     = (int*)ws;  ws += 512;
    int* capt_sorted = (int*)ws;  ws += 128 * MAXLEN * sizeof(int);
    ws = align256(ws);
    float* mean_feat = (float*)ws; ws += (size_t)128 * 2048 * 4;
    float* c         = (float*)ws; ws += (size_t)128 * 512 * 4;
    float* bsumP     = (float*)ws; ws += 2048 * 4;
    unsigned short* mean16   = (unsigned short*)ws; ws += (size_t)128 * 2048 * 2;
    unsigned short* hbuf0    = (unsigned short*)ws; ws += (size_t)128 * 512 * 2;
    unsigned short* hbuf1    = (unsigned short*)ws; ws += (size_t)128 * 512 * 2;
    unsigned short* awe16    = (unsigned short*)ws; ws += (size_t)128 * 2048 * 2;
    unsigned short* Wfb16    = (unsigned short*)ws; ws += (size_t)2048 * 512 * 2;
    unsigned short* WgP16    = (unsigned short*)ws; ws += (size_t)2048 * 3072 * 2;
    unsigned short* Wfc16    = (unsigned short*)ws; ws += (size_t)10000 * 512 * 2;
    unsigned short* Winith16 = (unsigned short*)ws; ws += (size_t)512 * 2048 * 2;
    unsigned short* Winitc16 = (unsigned short*)ws; ws += (size_t)512 * 2048 * 2;
    unsigned short* embs16   = (unsigned short*)ws; ws += (size_t)31 * 128 * 512 * 2;
    unsigned short* hnew_all = (unsigned short*)ws; ws += (size_t)31 * 128 * 512 * 2;

    sort_kernel<<<1, 128, 0, stream>>>(capt_lengths, enc_capt, sort_ind, dec_len,
                                       capt_sorted, out);
    mean_kernel<<<dim3(8, 128), 256, 0, stream>>>(enc_feature, sort_ind,
                                                  mean_feat, mean16);

    f32_to_bf16<<<(2048 * 512 / 4 + 255) / 256, 256, 0, stream>>>(W_fbeta, Wfb16, 2048 * 512);
    f32_to_bf16<<<(10000 * 512 / 4 + 255) / 256, 256, 0, stream>>>(W_fc, Wfc16, 10000 * 512);
    f32_to_bf16<<<(512 * 2048 / 4 + 255) / 256, 256, 0, stream>>>(W_inith, Winith16, 512 * 2048);
    f32_to_bf16<<<(512 * 2048 / 4 + 255) / 256, 256, 0, stream>>>(W_initc, Winitc16, 512 * 2048);
    concat_wg<<<dim3(12, 2048), 256, 0, stream>>>(W_ih, W_hh, WgP16);
    bsum_kernel<<<8, 256, 0, stream>>>(b_ih, b_hh, bsumP);
    embs_gather<<<(31 * 128 * 512 + 255) / 256, 256, 0, stream>>>(emb, capt_sorted, embs16);

    PP pp;
    pp.mean16 = mean16;   pp.mean_feat = mean_feat;
    pp.Wfb = Wfb16;       pp.b_fbeta = b_fbeta;
    pp.WgP = WgP16;       pp.bsumP = bsumP;
    pp.Winith = Winith16; pp.b_inith = b_inith;
    pp.Winitc = Winitc16; pp.b_initc = b_initc;
    pp.embs = embs16;     pp.c = c;
    pp.h0 = hbuf0;        pp.h1 = hbuf1;
    pp.awe = awe16;       pp.hnew_all = hnew_all;
    pp.dec_len = dec_len;
    void* args[] = { &pp };
    hipLaunchCooperativeKernel((const void*)persistent_kernel,
                               dim3(256), dim3(512), args, 0, stream);

    fc128x<<<2480, 256, 0, stream>>>(hnew_all, Wfc16, b_fc, dec_len, out);
    alphas_kernel<<<3038, 256, 0, stream>>>(dec_len, out);
}